// Round 13
// baseline (146.369 us; speedup 1.0000x reference)
//
#include <hip/hip_runtime.h>
#include <hip/hip_bf16.h>
#include <math.h>

#define B 32
#define T 512
#define D 512
#define H 8
#define DH 64
#define NEGV (-4294967295.0f)   // -(2^32) + 1
#define LN_EPS 1e-8f

typedef __attribute__((ext_vector_type(8))) short bf16x8;
typedef __attribute__((ext_vector_type(4))) float f32x4;

__device__ inline f32x4 mfma16(bf16x8 a, bf16x8 b, f32x4 c) {
    return __builtin_amdgcn_mfma_f32_16x16x32_bf16(a, b, c, 0, 0, 0);
}

__device__ inline float fexp2(float x) { return __builtin_amdgcn_exp2f(x); }

#define GLDS16(g, l)                                                      \
    __builtin_amdgcn_global_load_lds(                                     \
        (const __attribute__((address_space(1))) void*)(g),               \
        (__attribute__((address_space(3))) void*)(l), 16, 0, 0)

__device__ inline unsigned short bf16bits(float x) {
    __hip_bfloat16 h = __float2bfloat16(x);
    union { __hip_bfloat16 h; unsigned short u; } cv;
    cv.h = h;
    return cv.u;
}

__device__ inline float b2f(unsigned short u) {
    union { unsigned u; float f; } c;
    c.u = ((unsigned)u) << 16;
    return c.f;
}

// ---------------------------------------------------------------------------
// Kernel 1: convert queries/keys -> bf16 + row masks + W -> bf16 (merged).
// blocks x<4096: X conversion + masks.  x>=4096: W conversion (384 chunks).
// qmask: 0/1 multiplier.  kmask: ADDITIVE bias (0 valid, NEG masked).
// ---------------------------------------------------------------------------
__global__ __launch_bounds__(256) void convert_all(
    const float* __restrict__ queries, const float* __restrict__ keys,
    const float* __restrict__ Wq, const float* __restrict__ Wk,
    const float* __restrict__ Wv,
    __hip_bfloat16* __restrict__ Qx, __hip_bfloat16* __restrict__ Kx,
    __hip_bfloat16* __restrict__ Wbf,
    float* __restrict__ qmask, float* __restrict__ kmask)
{
    const int tid = threadIdx.x;
    if (blockIdx.x >= 4096) {
        const int i = (blockIdx.x - 4096) * 2 + blockIdx.y;   // 0..383
        const int mat = i >> 7;
        const float* Ws = (mat == 0) ? Wq : (mat == 1) ? Wk : Wv;
        const int idx = ((i & 127) * 256 + tid) * 8;
        float4 a = *(const float4*)&Ws[idx];
        float4 c = *(const float4*)&Ws[idx + 4];
        union { unsigned short u[8]; bf16x8 v; } pk;
        pk.u[0] = bf16bits(a.x); pk.u[1] = bf16bits(a.y);
        pk.u[2] = bf16bits(a.z); pk.u[3] = bf16bits(a.w);
        pk.u[4] = bf16bits(c.x); pk.u[5] = bf16bits(c.y);
        pk.u[6] = bf16bits(c.z); pk.u[7] = bf16bits(c.w);
        *(bf16x8*)&Wbf[(size_t)mat * 262144 + idx] = pk.v;
        return;
    }

    const int wid = tid >> 6;
    const int lane = tid & 63;
    const int row = blockIdx.x * 4 + wid;
    const float* src = blockIdx.y ? keys : queries;
    __hip_bfloat16* dst = blockIdx.y ? Kx : Qx;
    float* dm = blockIdx.y ? kmask : qmask;

    const float4* p = (const float4*)(src + (size_t)row * 512);
    float4 a = p[lane * 2];
    float4 c = p[lane * 2 + 1];
    float s = a.x + a.y + a.z + a.w + c.x + c.y + c.z + c.w;

    union { unsigned short u[8]; bf16x8 v; } pk;
    pk.u[0] = bf16bits(a.x); pk.u[1] = bf16bits(a.y);
    pk.u[2] = bf16bits(a.z); pk.u[3] = bf16bits(a.w);
    pk.u[4] = bf16bits(c.x); pk.u[5] = bf16bits(c.y);
    pk.u[6] = bf16bits(c.z); pk.u[7] = bf16bits(c.w);
    *(bf16x8*)&dst[(size_t)row * 512 + lane * 8] = pk.v;

#pragma unroll
    for (int off = 32; off > 0; off >>= 1) s += __shfl_xor(s, off, 64);
    if (lane == 0)
        dm[row] = blockIdx.y ? ((s != 0.0f) ? 0.0f : NEGV)
                             : ((s != 0.0f) ? 1.0f : 0.0f);
}

// ---------------------------------------------------------------------------
// Kernel 2a: Q/K projection, bf16 MFMA, SWAPPED operands mfma(W, X).
// ---------------------------------------------------------------------------
__global__ __launch_bounds__(256) void qkv_qk(
    const __hip_bfloat16* __restrict__ Qx, const __hip_bfloat16* __restrict__ Kx,
    const __hip_bfloat16* __restrict__ Wbf,
    const float* __restrict__ bq, const float* __restrict__ bk,
    __hip_bfloat16* __restrict__ Qbf, __hip_bfloat16* __restrict__ Kbf)
{
    const int mat = blockIdx.z;
    const __hip_bfloat16* X  = mat ? Kx : Qx;
    const __hip_bfloat16* Wm = Wbf + (size_t)mat * 262144;
    const float* bias = mat ? bk : bq;
    __hip_bfloat16* Out = mat ? Kbf : Qbf;
    const float sc = mat ? 1.0f : 0.18033688011112042f;

    const int bm = blockIdx.x * 128;
    const int bn = blockIdx.y * 128;
    const int tid = threadIdx.x;
    const int w = tid >> 6, lane = tid & 63;
    const int lo = lane & 15, hi = lane >> 4;
    const int wm = (w >> 1) * 64, wn = (w & 1) * 64;

    __shared__ __hip_bfloat16 As[2][128 * 32];
    __shared__ __hip_bfloat16 Bs[2][128 * 32];

    const int r0 = tid >> 2,          g0 = (tid & 3) ^ ((r0 >> 1) & 3);
    const int r1 = (tid + 256) >> 2,  g1 = ((tid + 256) & 3) ^ ((r1 >> 1) & 3);
    const __hip_bfloat16* sA0 = X  + (size_t)(bm + r0) * 512 + g0 * 8;
    const __hip_bfloat16* sA1 = X  + (size_t)(bm + r1) * 512 + g1 * 8;
    const __hip_bfloat16* sB0 = Wm + (size_t)(bn + r0) * 512 + g0 * 8;
    const __hip_bfloat16* sB1 = Wm + (size_t)(bn + r1) * 512 + g1 * 8;
    const int dst0 = (w * 64) * 8;
    const int dst1 = (256 + w * 64) * 8;

    int offA[4], offB[4];
#pragma unroll
    for (int mi = 0; mi < 4; ++mi) {
        int r = wm + mi * 16 + lo;
        offA[mi] = r * 32 + ((hi ^ ((r >> 1) & 3)) * 8);
    }
#pragma unroll
    for (int ni = 0; ni < 4; ++ni) {
        int r = wn + ni * 16 + lo;
        offB[ni] = r * 32 + ((hi ^ ((r >> 1) & 3)) * 8);
    }

    f32x4 acc[4][4];
#pragma unroll
    for (int mi = 0; mi < 4; ++mi)
#pragma unroll
        for (int ni = 0; ni < 4; ++ni)
            acc[mi][ni] = (f32x4){0.f, 0.f, 0.f, 0.f};

    GLDS16(sA0, &As[0][dst0]);
    GLDS16(sA1, &As[0][dst1]);
    GLDS16(sB0, &Bs[0][dst0]);
    GLDS16(sB1, &Bs[0][dst1]);
    __syncthreads();

    for (int kt = 0; kt < 16; ++kt) {
        const int cur = kt & 1;
        if (kt < 15) {
            const int k0 = (kt + 1) * 32;
            GLDS16(sA0 + k0, &As[cur ^ 1][dst0]);
            GLDS16(sA1 + k0, &As[cur ^ 1][dst1]);
            GLDS16(sB0 + k0, &Bs[cur ^ 1][dst0]);
            GLDS16(sB1 + k0, &Bs[cur ^ 1][dst1]);
        }
        bf16x8 af[4], bfr[4];
#pragma unroll
        for (int mi = 0; mi < 4; ++mi) af[mi]  = *(const bf16x8*)&As[cur][offA[mi]];
#pragma unroll
        for (int ni = 0; ni < 4; ++ni) bfr[ni] = *(const bf16x8*)&Bs[cur][offB[ni]];
#pragma unroll
        for (int mi = 0; mi < 4; ++mi)
#pragma unroll
            for (int ni = 0; ni < 4; ++ni)
                acc[mi][ni] = mfma16(bfr[ni], af[mi], acc[mi][ni]);
        __syncthreads();
    }

    float4 b4[4];
#pragma unroll
    for (int ni = 0; ni < 4; ++ni)
        b4[ni] = *(const float4*)&bias[bn + wn + ni * 16 + hi * 4];
#pragma unroll
    for (int mi = 0; mi < 4; ++mi) {
        const size_t tok = bm + wm + mi * 16 + lo;
        __hip_bfloat16* orow = Out + tok * 512 + bn + wn + hi * 4;
#pragma unroll
        for (int ni = 0; ni < 4; ++ni) {
            union { ushort4 u4; unsigned short us[4]; } pk;
            pk.us[0] = bf16bits((acc[mi][ni][0] + b4[ni].x) * sc);
            pk.us[1] = bf16bits((acc[mi][ni][1] + b4[ni].y) * sc);
            pk.us[2] = bf16bits((acc[mi][ni][2] + b4[ni].z) * sc);
            pk.us[3] = bf16bits((acc[mi][ni][3] + b4[ni].w) * sc);
            *(ushort4*)(orow + ni * 16) = pk.u4;
        }
    }
}

// ---------------------------------------------------------------------------
// Kernel 2b: V projection, bf16 MFMA, original order mfma(X, W).
// ---------------------------------------------------------------------------
__global__ __launch_bounds__(256) void qkv_v(
    const __hip_bfloat16* __restrict__ Kx, const __hip_bfloat16* __restrict__ Wbf,
    const float* __restrict__ bv, __hip_bfloat16* __restrict__ Vtb)
{
    const __hip_bfloat16* X  = Kx;
    const __hip_bfloat16* Wm = Wbf + (size_t)2 * 262144;
    const float* bias = bv;

    const int bm = blockIdx.x * 128;
    const int bn = blockIdx.y * 128;
    const int tid = threadIdx.x;
    const int w = tid >> 6, lane = tid & 63;
    const int lo = lane & 15, hi = lane >> 4;
    const int wm = (w >> 1) * 64, wn = (w & 1) * 64;

    __shared__ __hip_bfloat16 As[2][128 * 32];
    __shared__ __hip_bfloat16 Bs[2][128 * 32];

    const int r0 = tid >> 2,          g0 = (tid & 3) ^ ((r0 >> 1) & 3);
    const int r1 = (tid + 256) >> 2,  g1 = ((tid + 256) & 3) ^ ((r1 >> 1) & 3);
    const __hip_bfloat16* sA0 = X  + (size_t)(bm + r0) * 512 + g0 * 8;
    const __hip_bfloat16* sA1 = X  + (size_t)(bm + r1) * 512 + g1 * 8;
    const __hip_bfloat16* sB0 = Wm + (size_t)(bn + r0) * 512 + g0 * 8;
    const __hip_bfloat16* sB1 = Wm + (size_t)(bn + r1) * 512 + g1 * 8;
    const int dst0 = (w * 64) * 8;
    const int dst1 = (256 + w * 64) * 8;

    int offA[4], offB[4];
#pragma unroll
    for (int mi = 0; mi < 4; ++mi) {
        int r = wm + mi * 16 + lo;
        offA[mi] = r * 32 + ((hi ^ ((r >> 1) & 3)) * 8);
    }
#pragma unroll
    for (int ni = 0; ni < 4; ++ni) {
        int r = wn + ni * 16 + lo;
        offB[ni] = r * 32 + ((hi ^ ((r >> 1) & 3)) * 8);
    }

    f32x4 acc[4][4];
#pragma unroll
    for (int mi = 0; mi < 4; ++mi)
#pragma unroll
        for (int ni = 0; ni < 4; ++ni)
            acc[mi][ni] = (f32x4){0.f, 0.f, 0.f, 0.f};

    GLDS16(sA0, &As[0][dst0]);
    GLDS16(sA1, &As[0][dst1]);
    GLDS16(sB0, &Bs[0][dst0]);
    GLDS16(sB1, &Bs[0][dst1]);
    __syncthreads();

    for (int kt = 0; kt < 16; ++kt) {
        const int cur = kt & 1;
        if (kt < 15) {
            const int k0 = (kt + 1) * 32;
            GLDS16(sA0 + k0, &As[cur ^ 1][dst0]);
            GLDS16(sA1 + k0, &As[cur ^ 1][dst1]);
            GLDS16(sB0 + k0, &Bs[cur ^ 1][dst0]);
            GLDS16(sB1 + k0, &Bs[cur ^ 1][dst1]);
        }
        bf16x8 af[4], bfr[4];
#pragma unroll
        for (int mi = 0; mi < 4; ++mi) af[mi]  = *(const bf16x8*)&As[cur][offA[mi]];
#pragma unroll
        for (int ni = 0; ni < 4; ++ni) bfr[ni] = *(const bf16x8*)&Bs[cur][offB[ni]];
#pragma unroll
        for (int mi = 0; mi < 4; ++mi)
#pragma unroll
            for (int ni = 0; ni < 4; ++ni)
                acc[mi][ni] = mfma16(af[mi], bfr[ni], acc[mi][ni]);
        __syncthreads();
    }

    float bcol[4];
#pragma unroll
    for (int ni = 0; ni < 4; ++ni) bcol[ni] = bias[bn + wn + ni * 16 + lo];
    const int bb = bm >> 9;
    const int tb = (bm & 511) + wm;
#pragma unroll
    for (int ni = 0; ni < 4; ++ni) {
        const int n = bn + wn + ni * 16 + lo;
        const int hh = n >> 6, dh = n & 63;
#pragma unroll
        for (int mi = 0; mi < 4; ++mi) {
            const int tok = tb + mi * 16 + hi * 4;
            const int ktl = tok >> 6, tl = tok & 63;
            union { ushort4 u4; unsigned short us[4]; } pk;
#pragma unroll
            for (int j = 0; j < 4; ++j)
                pk.us[j] = bf16bits(acc[mi][ni][j] + bcol[ni]);
            *(ushort4*)(Vtb + ((((size_t)(bb * 8 + hh) * 8 + ktl) * 64 + dh) * 64 + tl))
                = pk.u4;
        }
    }
}

// ---------------------------------------------------------------------------
// Kernel 3: flash attention — round-10 sync structure, plus:
//  - issue order km -> vf -> STAGE (stage is newest, survives PV's vf drain
//    -> prefetch gets a full iteration of flight); vmcnt(12)/vmcnt(10)
//  - s_setprio(1) around QK and PV MFMA clusters (T5)
//  - defer-max: skip o-rescale when max grows < 8 (log2 domain, T13)
// ---------------------------------------------------------------------------
__global__ __launch_bounds__(256, 4) void flash_attn(
    const __hip_bfloat16* __restrict__ Qbf, const __hip_bfloat16* __restrict__ Kbf,
    const __hip_bfloat16* __restrict__ Vtb, const float* __restrict__ qmask,
    const float* __restrict__ kmneg, __hip_bfloat16* __restrict__ Oattn)
{
    const int flat = blockIdx.x + (blockIdx.y << 2) + (blockIdx.z << 5);
    const int rm = ((flat & 7) << 7) + (flat >> 3);
    const int pr = rm & 3;
    const int h  = (rm >> 2) & 7;
    const int b  = rm >> 5;

    const int tid  = threadIdx.x;
    const int w    = tid >> 6;
    const int lane = tid & 63;
    const int lo = lane & 15;
    const int hi = lane >> 4;

    __shared__ __hip_bfloat16 Ks[2][4096];
    __shared__ __hip_bfloat16 p_lds[4][16][72];

    const float* km = kmneg + b * T;
    const __hip_bfloat16* Kh = Kbf + (size_t)b * T * D + h * DH;
    const __hip_bfloat16* Vh = Vtb + (size_t)(b * H + h) * T * DH;

    const int sr0 = tid >> 3,         sg0 = (tid & 7) ^ (sr0 & 7);
    const int sr1 = (tid + 256) >> 3, sg1 = ((tid + 256) & 7) ^ (sr1 & 7);
    const __hip_bfloat16* sK0 = Kh + (size_t)sr0 * 512 + sg0 * 8;
    const __hip_bfloat16* sK1 = Kh + (size_t)sr1 * 512 + sg1 * 8;
    __hip_bfloat16* dK0a = &Ks[0][w * 512];
    __hip_bfloat16* dK0b = &Ks[0][2048 + w * 512];
    __hip_bfloat16* dK1a = &Ks[1][w * 512];
    __hip_bfloat16* dK1b = &Ks[1][2048 + w * 512];

#define STAGEK(bufp, kt) do {                                              \
        const size_t _o = (size_t)(kt) * 32768;                            \
        GLDS16(sK0 + _o, (bufp) ? dK1a : dK0a);                            \
        GLDS16(sK1 + _o, (bufp) ? dK1b : dK0b);                            \
    } while (0)

    int kfoff[4][2];
#pragma unroll
    for (int c = 0; c < 4; ++c)
#pragma unroll
        for (int j = 0; j < 2; ++j)
            kfoff[c][j] = (c * 16 + lo) * 64 + (((j * 4 + hi) ^ (lo & 7)) * 8);

    // static causal bias for the diagonal tile (tile-local key vs q indices)
    f32x4 cb[4];
#pragma unroll
    for (int c = 0; c < 4; ++c)
#pragma unroll
        for (int j = 0; j < 4; ++j)
            cb[c][j] = (c * 16 + hi * 4 + j <= w * 16 + lo) ? 0.0f : NEGV;

    const int nt1 = pr + 1;

    int qtile = pr;
    int q = qtile * 64 + w * 16 + lo;
    const __hip_bfloat16* Qrow = Qbf + (size_t)(b * T + q) * D + h * DH;
    bf16x8 qf0 = *(const bf16x8*)(Qrow + hi * 8);
    bf16x8 qf1 = *(const bf16x8*)(Qrow + 32 + hi * 8);

    f32x4 o[4];
    float mrun = -INFINITY, lrun = 0.f;
#pragma unroll
    for (int d = 0; d < 4; ++d) o[d] = (f32x4){0.f, 0.f, 0.f, 0.f};

    STAGEK(0, 0);

    for (int i = 0; i < 9; ++i) {
        const int cur = i & 1;
        const bool diag = (i == nt1 - 1) || (i == 8);
        const int kt = (i < nt1) ? i : (i - nt1);
        const int kb = kt * 64;

        // ---- km (oldest), then V fragments, then stage (newest) ----
        f32x4 kmb[4];
#pragma unroll
        for (int c = 0; c < 4; ++c)
            kmb[c] = *(const f32x4*)(km + kb + c * 16 + hi * 4);

        const __hip_bfloat16* Vtile = Vh + (size_t)kt * 4096;
        bf16x8 vf[4][2];
#pragma unroll
        for (int db = 0; db < 4; ++db) {
            const __hip_bfloat16* Vrow = Vtile + (db * 16 + lo) * 64;
            vf[db][0] = *(const bf16x8*)(Vrow + hi * 8);
            vf[db][1] = *(const bf16x8*)(Vrow + 32 + hi * 8);
        }
        __builtin_amdgcn_sched_barrier(0);   // pin: stage issues after km/vf

        if (i < 8) {
            const int nxt = (i + 1 < nt1) ? (i + 1) : (i + 1 - nt1);
            STAGEK(cur ^ 1, nxt);
            // 12 just-issued (2 km-x4 + 8 vf + 2 stage) stay; waits prev stage
            asm volatile("s_waitcnt vmcnt(12)" ::: "memory");
        } else {
            asm volatile("s_waitcnt vmcnt(10)" ::: "memory");
        }
        __builtin_amdgcn_s_barrier();
        __builtin_amdgcn_sched_barrier(0);

        if (i == nt1) {
            const float inv = qmask[b * T + q] / lrun;
            __hip_bfloat16* orow = Oattn + (size_t)(b * T + q) * D + h * DH;
#pragma unroll
            for (int db = 0; db < 4; ++db) {
                union { ushort4 u4; unsigned short us[4]; } pk;
#pragma unroll
                for (int j = 0; j < 4; ++j)
                    pk.us[j] = bf16bits(o[db][j] * inv);
                *(ushort4*)(orow + db * 16 + hi * 4) = pk.u4;
            }
            qtile = 7 - pr;
            q = qtile * 64 + w * 16 + lo;
            const __hip_bfloat16* Qrow2 = Qbf + (size_t)(b * T + q) * D + h * DH;
            qf0 = *(const bf16x8*)(Qrow2 + hi * 8);
            qf1 = *(const bf16x8*)(Qrow2 + 32 + hi * 8);
            mrun = -INFINITY; lrun = 0.f;
#pragma unroll
            for (int d = 0; d < 4; ++d) o[d] = (f32x4){0.f, 0.f, 0.f, 0.f};
        }

        bf16x8 kf[4][2];
#pragma unroll
        for (int c = 0; c < 4; ++c) {
            kf[c][0] = *(const bf16x8*)&Ks[cur][kfoff[c][0]];
            kf[c][1] = *(const bf16x8*)&Ks[cur][kfoff[c][1]];
        }

        // ---- S^T + additive masks ----
        __builtin_amdgcn_s_setprio(1);
        f32x4 S[4];
#pragma unroll
        for (int c = 0; c < 4; ++c) {
            f32x4 acc = (f32x4){0.f, 0.f, 0.f, 0.f};
            acc = mfma16(kf[c][0], qf0, acc);
            acc = mfma16(kf[c][1], qf1, acc);
            acc += kmb[c];
            if (diag) acc += cb[c];
            S[c] = acc;
        }
        __builtin_amdgcn_s_setprio(0);

        float tm0 = fmaxf(fmaxf(S[0][0], S[0][1]), fmaxf(S[0][2], S[0][3]));
        float tm1 = fmaxf(fmaxf(S[1][0], S[1][1]), fmaxf(S[1][2], S[1][3]));
        float tm2 = fmaxf(fmaxf(S[2][0], S[2][1]), fmaxf(S[2][2], S[2][3]));
        float tm3 = fmaxf(fmaxf(S[3][0], S[3][1]), fmaxf(S[3][2], S[3][3]));
        float tm = fmaxf(fmaxf(tm0, tm1), fmaxf(tm2, tm3));
        tm = fmaxf(tm, __shfl_xor(tm, 16, 64));
        tm = fmaxf(tm, __shfl_xor(tm, 32, 64));

        // defer-max (T13): only rescale when the running max grew by > 8
        if (!__all(tm <= mrun + 8.0f)) {
            const float nm = fmaxf(mrun, tm);
            const float alpha = fexp2(mrun - nm);
            mrun = nm;
#pragma unroll
            for (int d = 0; d < 4; ++d)
#pragma unroll
                for (int j = 0; j < 4; ++j)
                    o[d][j] *= alpha;
            lrun *= alpha;
        }

        float ps = 0.f;
#pragma unroll
        for (int c = 0; c < 4; ++c) {
            union { ushort4 u4; unsigned short us[4]; } pk;
#pragma unroll
            for (int j = 0; j < 4; ++j) {
                float p = fexp2(S[c][j] - mrun);
                ps += p;
                pk.us[j] = bf16bits(p);
            }
            *(ushort4*)&p_lds[w][lo][c * 16 + hi * 4] = pk.u4;
        }
        ps += __shfl_xor(ps, 16, 64);
        ps += __shfl_xor(ps, 32, 64);
        lrun += ps;

        asm volatile("s_waitcnt lgkmcnt(0)" ::: "memory");
        __builtin_amdgcn_sched_barrier(0);

        __builtin_amdgcn_s_setprio(1);
#pragma unroll
        for (int half = 0; half < 2; ++half) {
            bf16x8 pf = *(const bf16x8*)&p_lds[w][lo][half * 32 + hi * 8];
#pragma unroll
            for (int db = 0; db < 4; ++db)
                o[db] = mfma16(vf[db][half], pf, o[db]);
        }
        __builtin_amdgcn_s_setprio(0);

        __builtin_amdgcn_s_barrier();
    }

    {
        const float inv = qmask[b * T + q] / lrun;
        __hip_bfloat16* orow = Oattn + (size_t)(b * T + q) * D + h * DH;
#pragma unroll
        for (int db = 0; db < 4; ++db) {
            union { ushort4 u4; unsigned short us[4]; } pk;
#pragma unroll
            for (int j = 0; j < 4; ++j)
                pk.us[j] = bf16bits(o[db][j] * inv);
            *(ushort4*)(orow + db * 16 + hi * 4) = pk.u4;
        }
    }
#undef STAGEK
}

// ---------------------------------------------------------------------------
// Kernel 4: residual + LayerNorm (ddof=1, eps added to std).
// One WAVE per row: 8 elements/lane, shuffle-only reduction, no LDS/barriers.
// ---------------------------------------------------------------------------
__global__ __launch_bounds__(256) void resid_ln(
    const __hip_bfloat16* __restrict__ Oa, const float* __restrict__ queries,
    const float* __restrict__ gamma, const float* __restrict__ beta,
    float* __restrict__ out)
{
    const int w = threadIdx.x >> 6;
    const int lane = threadIdx.x & 63;
    const int row = blockIdx.x * 4 + w;
    const size_t base = (size_t)row * 512 + lane * 8;

    bf16x8 oa = *(const bf16x8*)((const unsigned short*)Oa + base);
    float4 q0 = *(const float4*)(queries + base);
    float4 q1 = *(const float4*)(queries + base + 4);

    float x[8];
    x[0] = b2f((unsigned short)oa[0]) + q0.x;
    x[1] = b2f((unsigned short)oa[1]) + q0.y;
    x[2] = b2f((unsigned short)oa[2]) + q0.z;
    x[3] = b2f((unsigned short)oa[3]) + q0.w;
    x[4] = b2f((unsigned short)oa[4]) + q1.x;
    x[5] = b2f((unsigned short)oa[5]) + q1.y;
    x[6] = b2f((unsigned short)oa[6]) + q1.z;
    x[7] = b2f((unsigned short)oa[7]) + q1.w;

    float s = ((x[0] + x[1]) + (x[2] + x[3])) + ((x[4] + x[5]) + (x[6] + x[7]));
#pragma unroll
    for (int off = 32; off > 0; off >>= 1) s += __shfl_xor(s, off, 64);
    const float mean = s * (1.0f / 512.0f);

    float d[8], ss = 0.f;
#pragma unroll
    for (int j = 0; j < 8; ++j) { d[j] = x[j] - mean; ss += d[j] * d[j]; }
#pragma unroll
    for (int off = 32; off > 0; off >>= 1) ss += __shfl_xor(ss, off, 64);
    const float denom = sqrtf(ss * (1.0f / 511.0f)) + LN_EPS;
    const float rden = 1.0f / denom;

    float4 g0 = *(const float4*)(gamma + lane * 8);
    float4 g1 = *(const float4*)(gamma + lane * 8 + 4);
    float4 b0 = *(const float4*)(beta + lane * 8);
    float4 b1 = *(const float4*)(beta + lane * 8 + 4);

    float4 r0, r1;
    r0.x = g0.x * d[0] * rden + b0.x;
    r0.y = g0.y * d[1] * rden + b0.y;
    r0.z = g0.z * d[2] * rden + b0.z;
    r0.w = g0.w * d[3] * rden + b0.w;
    r1.x = g1.x * d[4] * rden + b1.x;
    r1.y = g1.y * d[5] * rden + b1.y;
    r1.z = g1.z * d[6] * rden + b1.z;
    r1.w = g1.w * d[7] * rden + b1.w;
    *(float4*)(out + base) = r0;
    *(float4*)(out + base + 4) = r1;
}

// ---------------------------------------------------------------------------
extern "C" void kernel_launch(void* const* d_in, const int* in_sizes, int n_in,
                              void* d_out, int out_size, void* d_ws, size_t ws_size,
                              hipStream_t stream)
{
    const float* queries = (const float*)d_in[0];
    const float* keys    = (const float*)d_in[1];
    const float* Wq      = (const float*)d_in[2];
    const float* bq      = (const float*)d_in[3];
    const float* Wk      = (const float*)d_in[4];
    const float* bk      = (const float*)d_in[5];
    const float* Wv      = (const float*)d_in[6];
    const float* bv      = (const float*)d_in[7];
    const float* gamma   = (const float*)d_in[8];
    const float* beta    = (const float*)d_in[9];
    float* out = (float*)d_out;

    char* ws = (char*)d_ws;
    __hip_bfloat16* Qbf   = (__hip_bfloat16*)(ws);                  // 16 MB
    __hip_bfloat16* Kbf   = (__hip_bfloat16*)(ws + 16777216);       // 16 MB
    __hip_bfloat16* Vtb   = (__hip_bfloat16*)(ws + 33554432);       // 16 MB
    __hip_bfloat16* Qx    = (__hip_bfloat16*)(ws + 50331648);       // 16 MB
    __hip_bfloat16* Oattn = (__hip_bfloat16*)(ws + 50331648);       // aliases Qx (dead)
    __hip_bfloat16* Kx    = (__hip_bfloat16*)(ws + 67108864);       // 16 MB
    __hip_bfloat16* Wbf   = (__hip_bfloat16*)(ws + 83886080);       // 1.5 MB
    float* qmask          = (float*)(ws + 85458944);                // 64 KB
    float* kmask          = (float*)(ws + 85524480);                // 64 KB

    convert_all<<<dim3(4288, 2), 256, 0, stream>>>(
        queries, keys, Wq, Wk, Wv, Qx, Kx, Wbf, qmask, kmask);
    qkv_qk<<<dim3(128, 4, 2), 256, 0, stream>>>(
        Qx, Kx, Wbf, bq, bk, Qbf, Kbf);
    qkv_v<<<dim3(128, 4), 256, 0, stream>>>(Kx, Wbf, bv, Vtb);
    flash_attn<<<dim3(4, 8, 32), 256, 0, stream>>>(
        Qbf, Kbf, Vtb, qmask, kmask, Oattn);
    resid_ln<<<4096, 256, 0, stream>>>(Oattn, queries, gamma, beta, out);
}

// Round 14
// 128.218 us; speedup vs baseline: 1.1416x; 1.1416x over previous
//
#include <hip/hip_runtime.h>
#include <hip/hip_bf16.h>
#include <math.h>

#define B 32
#define T 512
#define D 512
#define H 8
#define DH 64
#define NEGV (-4294967295.0f)   // -(2^32) + 1
#define LN_EPS 1e-8f

typedef __attribute__((ext_vector_type(8))) short bf16x8;
typedef __attribute__((ext_vector_type(4))) float f32x4;

__device__ inline f32x4 mfma16(bf16x8 a, bf16x8 b, f32x4 c) {
    return __builtin_amdgcn_mfma_f32_16x16x32_bf16(a, b, c, 0, 0, 0);
}

__device__ inline float fexp2(float x) { return __builtin_amdgcn_exp2f(x); }

#define GLDS16(g, l)                                                      \
    __builtin_amdgcn_global_load_lds(                                     \
        (const __attribute__((address_space(1))) void*)(g),               \
        (__attribute__((address_space(3))) void*)(l), 16, 0, 0)

__device__ inline unsigned short bf16bits(float x) {
    __hip_bfloat16 h = __float2bfloat16(x);
    union { __hip_bfloat16 h; unsigned short u; } cv;
    cv.h = h;
    return cv.u;
}

__device__ inline float b2f(unsigned short u) {
    union { unsigned u; float f; } c;
    c.u = ((unsigned)u) << 16;
    return c.f;
}

// ---------------------------------------------------------------------------
// Kernel 1: convert queries/keys -> bf16 + row masks + W -> bf16 (merged).
// blocks x<4096: X conversion + masks.  x>=4096: W conversion (384 chunks).
// qmask: 0/1 multiplier.  kmask: ADDITIVE bias (0 valid, NEG masked).
// ---------------------------------------------------------------------------
__global__ __launch_bounds__(256) void convert_all(
    const float* __restrict__ queries, const float* __restrict__ keys,
    const float* __restrict__ Wq, const float* __restrict__ Wk,
    const float* __restrict__ Wv,
    __hip_bfloat16* __restrict__ Qx, __hip_bfloat16* __restrict__ Kx,
    __hip_bfloat16* __restrict__ Wbf,
    float* __restrict__ qmask, float* __restrict__ kmask)
{
    const int tid = threadIdx.x;
    if (blockIdx.x >= 4096) {
        const int i = (blockIdx.x - 4096) * 2 + blockIdx.y;   // 0..383
        const int mat = i >> 7;
        const float* Ws = (mat == 0) ? Wq : (mat == 1) ? Wk : Wv;
        const int idx = ((i & 127) * 256 + tid) * 8;
        float4 a = *(const float4*)&Ws[idx];
        float4 c = *(const float4*)&Ws[idx + 4];
        union { unsigned short u[8]; bf16x8 v; } pk;
        pk.u[0] = bf16bits(a.x); pk.u[1] = bf16bits(a.y);
        pk.u[2] = bf16bits(a.z); pk.u[3] = bf16bits(a.w);
        pk.u[4] = bf16bits(c.x); pk.u[5] = bf16bits(c.y);
        pk.u[6] = bf16bits(c.z); pk.u[7] = bf16bits(c.w);
        *(bf16x8*)&Wbf[(size_t)mat * 262144 + idx] = pk.v;
        return;
    }

    const int wid = tid >> 6;
    const int lane = tid & 63;
    const int row = blockIdx.x * 4 + wid;
    const float* src = blockIdx.y ? keys : queries;
    __hip_bfloat16* dst = blockIdx.y ? Kx : Qx;
    float* dm = blockIdx.y ? kmask : qmask;

    const float4* p = (const float4*)(src + (size_t)row * 512);
    float4 a = p[lane * 2];
    float4 c = p[lane * 2 + 1];
    float s = a.x + a.y + a.z + a.w + c.x + c.y + c.z + c.w;

    union { unsigned short u[8]; bf16x8 v; } pk;
    pk.u[0] = bf16bits(a.x); pk.u[1] = bf16bits(a.y);
    pk.u[2] = bf16bits(a.z); pk.u[3] = bf16bits(a.w);
    pk.u[4] = bf16bits(c.x); pk.u[5] = bf16bits(c.y);
    pk.u[6] = bf16bits(c.z); pk.u[7] = bf16bits(c.w);
    *(bf16x8*)&dst[(size_t)row * 512 + lane * 8] = pk.v;

#pragma unroll
    for (int off = 32; off > 0; off >>= 1) s += __shfl_xor(s, off, 64);
    if (lane == 0)
        dm[row] = blockIdx.y ? ((s != 0.0f) ? 0.0f : NEGV)
                             : ((s != 0.0f) ? 1.0f : 0.0f);
}

// ---------------------------------------------------------------------------
// Kernel 2a: Q/K projection, bf16 MFMA, SWAPPED operands mfma(W, X).
// ---------------------------------------------------------------------------
__global__ __launch_bounds__(256) void qkv_qk(
    const __hip_bfloat16* __restrict__ Qx, const __hip_bfloat16* __restrict__ Kx,
    const __hip_bfloat16* __restrict__ Wbf,
    const float* __restrict__ bq, const float* __restrict__ bk,
    __hip_bfloat16* __restrict__ Qbf, __hip_bfloat16* __restrict__ Kbf)
{
    const int mat = blockIdx.z;
    const __hip_bfloat16* X  = mat ? Kx : Qx;
    const __hip_bfloat16* Wm = Wbf + (size_t)mat * 262144;
    const float* bias = mat ? bk : bq;
    __hip_bfloat16* Out = mat ? Kbf : Qbf;
    const float sc = mat ? 1.0f : 0.18033688011112042f;

    const int bm = blockIdx.x * 128;
    const int bn = blockIdx.y * 128;
    const int tid = threadIdx.x;
    const int w = tid >> 6, lane = tid & 63;
    const int lo = lane & 15, hi = lane >> 4;
    const int wm = (w >> 1) * 64, wn = (w & 1) * 64;

    __shared__ __hip_bfloat16 As[2][128 * 32];
    __shared__ __hip_bfloat16 Bs[2][128 * 32];

    const int r0 = tid >> 2,          g0 = (tid & 3) ^ ((r0 >> 1) & 3);
    const int r1 = (tid + 256) >> 2,  g1 = ((tid + 256) & 3) ^ ((r1 >> 1) & 3);
    const __hip_bfloat16* sA0 = X  + (size_t)(bm + r0) * 512 + g0 * 8;
    const __hip_bfloat16* sA1 = X  + (size_t)(bm + r1) * 512 + g1 * 8;
    const __hip_bfloat16* sB0 = Wm + (size_t)(bn + r0) * 512 + g0 * 8;
    const __hip_bfloat16* sB1 = Wm + (size_t)(bn + r1) * 512 + g1 * 8;
    const int dst0 = (w * 64) * 8;
    const int dst1 = (256 + w * 64) * 8;

    int offA[4], offB[4];
#pragma unroll
    for (int mi = 0; mi < 4; ++mi) {
        int r = wm + mi * 16 + lo;
        offA[mi] = r * 32 + ((hi ^ ((r >> 1) & 3)) * 8);
    }
#pragma unroll
    for (int ni = 0; ni < 4; ++ni) {
        int r = wn + ni * 16 + lo;
        offB[ni] = r * 32 + ((hi ^ ((r >> 1) & 3)) * 8);
    }

    f32x4 acc[4][4];
#pragma unroll
    for (int mi = 0; mi < 4; ++mi)
#pragma unroll
        for (int ni = 0; ni < 4; ++ni)
            acc[mi][ni] = (f32x4){0.f, 0.f, 0.f, 0.f};

    GLDS16(sA0, &As[0][dst0]);
    GLDS16(sA1, &As[0][dst1]);
    GLDS16(sB0, &Bs[0][dst0]);
    GLDS16(sB1, &Bs[0][dst1]);
    __syncthreads();

    for (int kt = 0; kt < 16; ++kt) {
        const int cur = kt & 1;
        if (kt < 15) {
            const int k0 = (kt + 1) * 32;
            GLDS16(sA0 + k0, &As[cur ^ 1][dst0]);
            GLDS16(sA1 + k0, &As[cur ^ 1][dst1]);
            GLDS16(sB0 + k0, &Bs[cur ^ 1][dst0]);
            GLDS16(sB1 + k0, &Bs[cur ^ 1][dst1]);
        }
        bf16x8 af[4], bfr[4];
#pragma unroll
        for (int mi = 0; mi < 4; ++mi) af[mi]  = *(const bf16x8*)&As[cur][offA[mi]];
#pragma unroll
        for (int ni = 0; ni < 4; ++ni) bfr[ni] = *(const bf16x8*)&Bs[cur][offB[ni]];
#pragma unroll
        for (int mi = 0; mi < 4; ++mi)
#pragma unroll
            for (int ni = 0; ni < 4; ++ni)
                acc[mi][ni] = mfma16(bfr[ni], af[mi], acc[mi][ni]);
        __syncthreads();
    }

    float4 b4[4];
#pragma unroll
    for (int ni = 0; ni < 4; ++ni)
        b4[ni] = *(const float4*)&bias[bn + wn + ni * 16 + hi * 4];
#pragma unroll
    for (int mi = 0; mi < 4; ++mi) {
        const size_t tok = bm + wm + mi * 16 + lo;
        __hip_bfloat16* orow = Out + tok * 512 + bn + wn + hi * 4;
#pragma unroll
        for (int ni = 0; ni < 4; ++ni) {
            union { ushort4 u4; unsigned short us[4]; } pk;
            pk.us[0] = bf16bits((acc[mi][ni][0] + b4[ni].x) * sc);
            pk.us[1] = bf16bits((acc[mi][ni][1] + b4[ni].y) * sc);
            pk.us[2] = bf16bits((acc[mi][ni][2] + b4[ni].z) * sc);
            pk.us[3] = bf16bits((acc[mi][ni][3] + b4[ni].w) * sc);
            *(ushort4*)(orow + ni * 16) = pk.u4;
        }
    }
}

// ---------------------------------------------------------------------------
// Kernel 2b: V projection, bf16 MFMA, original order mfma(X, W).
// ---------------------------------------------------------------------------
__global__ __launch_bounds__(256) void qkv_v(
    const __hip_bfloat16* __restrict__ Kx, const __hip_bfloat16* __restrict__ Wbf,
    const float* __restrict__ bv, __hip_bfloat16* __restrict__ Vtb)
{
    const __hip_bfloat16* X  = Kx;
    const __hip_bfloat16* Wm = Wbf + (size_t)2 * 262144;
    const float* bias = bv;

    const int bm = blockIdx.x * 128;
    const int bn = blockIdx.y * 128;
    const int tid = threadIdx.x;
    const int w = tid >> 6, lane = tid & 63;
    const int lo = lane & 15, hi = lane >> 4;
    const int wm = (w >> 1) * 64, wn = (w & 1) * 64;

    __shared__ __hip_bfloat16 As[2][128 * 32];
    __shared__ __hip_bfloat16 Bs[2][128 * 32];

    const int r0 = tid >> 2,          g0 = (tid & 3) ^ ((r0 >> 1) & 3);
    const int r1 = (tid + 256) >> 2,  g1 = ((tid + 256) & 3) ^ ((r1 >> 1) & 3);
    const __hip_bfloat16* sA0 = X  + (size_t)(bm + r0) * 512 + g0 * 8;
    const __hip_bfloat16* sA1 = X  + (size_t)(bm + r1) * 512 + g1 * 8;
    const __hip_bfloat16* sB0 = Wm + (size_t)(bn + r0) * 512 + g0 * 8;
    const __hip_bfloat16* sB1 = Wm + (size_t)(bn + r1) * 512 + g1 * 8;
    const int dst0 = (w * 64) * 8;
    const int dst1 = (256 + w * 64) * 8;

    int offA[4], offB[4];
#pragma unroll
    for (int mi = 0; mi < 4; ++mi) {
        int r = wm + mi * 16 + lo;
        offA[mi] = r * 32 + ((hi ^ ((r >> 1) & 3)) * 8);
    }
#pragma unroll
    for (int ni = 0; ni < 4; ++ni) {
        int r = wn + ni * 16 + lo;
        offB[ni] = r * 32 + ((hi ^ ((r >> 1) & 3)) * 8);
    }

    f32x4 acc[4][4];
#pragma unroll
    for (int mi = 0; mi < 4; ++mi)
#pragma unroll
        for (int ni = 0; ni < 4; ++ni)
            acc[mi][ni] = (f32x4){0.f, 0.f, 0.f, 0.f};

    GLDS16(sA0, &As[0][dst0]);
    GLDS16(sA1, &As[0][dst1]);
    GLDS16(sB0, &Bs[0][dst0]);
    GLDS16(sB1, &Bs[0][dst1]);
    __syncthreads();

    for (int kt = 0; kt < 16; ++kt) {
        const int cur = kt & 1;
        if (kt < 15) {
            const int k0 = (kt + 1) * 32;
            GLDS16(sA0 + k0, &As[cur ^ 1][dst0]);
            GLDS16(sA1 + k0, &As[cur ^ 1][dst1]);
            GLDS16(sB0 + k0, &Bs[cur ^ 1][dst0]);
            GLDS16(sB1 + k0, &Bs[cur ^ 1][dst1]);
        }
        bf16x8 af[4], bfr[4];
#pragma unroll
        for (int mi = 0; mi < 4; ++mi) af[mi]  = *(const bf16x8*)&As[cur][offA[mi]];
#pragma unroll
        for (int ni = 0; ni < 4; ++ni) bfr[ni] = *(const bf16x8*)&Bs[cur][offB[ni]];
#pragma unroll
        for (int mi = 0; mi < 4; ++mi)
#pragma unroll
            for (int ni = 0; ni < 4; ++ni)
                acc[mi][ni] = mfma16(af[mi], bfr[ni], acc[mi][ni]);
        __syncthreads();
    }

    float bcol[4];
#pragma unroll
    for (int ni = 0; ni < 4; ++ni) bcol[ni] = bias[bn + wn + ni * 16 + lo];
    const int bb = bm >> 9;
    const int tb = (bm & 511) + wm;
#pragma unroll
    for (int ni = 0; ni < 4; ++ni) {
        const int n = bn + wn + ni * 16 + lo;
        const int hh = n >> 6, dh = n & 63;
#pragma unroll
        for (int mi = 0; mi < 4; ++mi) {
            const int tok = tb + mi * 16 + hi * 4;
            const int ktl = tok >> 6, tl = tok & 63;
            union { ushort4 u4; unsigned short us[4]; } pk;
#pragma unroll
            for (int j = 0; j < 4; ++j)
                pk.us[j] = bf16bits(acc[mi][ni][j] + bcol[ni]);
            *(ushort4*)(Vtb + ((((size_t)(bb * 8 + hh) * 8 + ktl) * 64 + dh) * 64 + tl))
                = pk.u4;
        }
    }
}

// ---------------------------------------------------------------------------
// Kernel 3: flash attention — round-12 version VERBATIM (tight lockstep:
// double-buffer Ks, stage->vmcnt(2)->barrier, two barriers/iter; static
// additive masks).  Round-11/13 lesson: any loosening of this pipeline
// doubles FETCH_SIZE (cross-block L2 temporal reuse is load-bearing).
// ---------------------------------------------------------------------------
__global__ __launch_bounds__(256, 4) void flash_attn(
    const __hip_bfloat16* __restrict__ Qbf, const __hip_bfloat16* __restrict__ Kbf,
    const __hip_bfloat16* __restrict__ Vtb, const float* __restrict__ qmask,
    const float* __restrict__ kmneg, __hip_bfloat16* __restrict__ Oattn)
{
    const int flat = blockIdx.x + (blockIdx.y << 2) + (blockIdx.z << 5);
    const int rm = ((flat & 7) << 7) + (flat >> 3);
    const int pr = rm & 3;
    const int h  = (rm >> 2) & 7;
    const int b  = rm >> 5;

    const int tid  = threadIdx.x;
    const int w    = tid >> 6;
    const int lane = tid & 63;
    const int lo = lane & 15;
    const int hi = lane >> 4;

    __shared__ __hip_bfloat16 Ks[2][4096];
    __shared__ __hip_bfloat16 p_lds[4][16][72];

    const float* km = kmneg + b * T;
    const __hip_bfloat16* Kh = Kbf + (size_t)b * T * D + h * DH;
    const __hip_bfloat16* Vh = Vtb + (size_t)(b * H + h) * T * DH;

    const int sr0 = tid >> 3,         sg0 = (tid & 7) ^ (sr0 & 7);
    const int sr1 = (tid + 256) >> 3, sg1 = ((tid + 256) & 7) ^ (sr1 & 7);
    const __hip_bfloat16* sK0 = Kh + (size_t)sr0 * 512 + sg0 * 8;
    const __hip_bfloat16* sK1 = Kh + (size_t)sr1 * 512 + sg1 * 8;
    __hip_bfloat16* dK0a = &Ks[0][w * 512];
    __hip_bfloat16* dK0b = &Ks[0][2048 + w * 512];
    __hip_bfloat16* dK1a = &Ks[1][w * 512];
    __hip_bfloat16* dK1b = &Ks[1][2048 + w * 512];

#define STAGEK(bufp, kt) do {                                              \
        const size_t _o = (size_t)(kt) * 32768;                            \
        GLDS16(sK0 + _o, (bufp) ? dK1a : dK0a);                            \
        GLDS16(sK1 + _o, (bufp) ? dK1b : dK0b);                            \
    } while (0)

    int kfoff[4][2];
#pragma unroll
    for (int c = 0; c < 4; ++c)
#pragma unroll
        for (int j = 0; j < 2; ++j)
            kfoff[c][j] = (c * 16 + lo) * 64 + (((j * 4 + hi) ^ (lo & 7)) * 8);

    // static causal bias for the diagonal tile (tile-local key vs q indices)
    f32x4 cb[4];
#pragma unroll
    for (int c = 0; c < 4; ++c)
#pragma unroll
        for (int j = 0; j < 4; ++j)
            cb[c][j] = (c * 16 + hi * 4 + j <= w * 16 + lo) ? 0.0f : NEGV;

    const int nt1 = pr + 1;

    int qtile = pr;
    int q = qtile * 64 + w * 16 + lo;
    const __hip_bfloat16* Qrow = Qbf + (size_t)(b * T + q) * D + h * DH;
    bf16x8 qf0 = *(const bf16x8*)(Qrow + hi * 8);
    bf16x8 qf1 = *(const bf16x8*)(Qrow + 32 + hi * 8);

    f32x4 o[4];
    float mrun = -INFINITY, lrun = 0.f;
#pragma unroll
    for (int d = 0; d < 4; ++d) o[d] = (f32x4){0.f, 0.f, 0.f, 0.f};

    STAGEK(0, 0);

    for (int i = 0; i < 9; ++i) {
        const int cur = i & 1;
        const bool diag = (i == nt1 - 1) || (i == 8);
        if (i < 8) {
            const int nxt = (i + 1 < nt1) ? (i + 1) : (i + 1 - nt1);
            STAGEK(cur ^ 1, nxt);
            asm volatile("s_waitcnt vmcnt(2)" ::: "memory");
        } else {
            asm volatile("s_waitcnt vmcnt(0)" ::: "memory");
        }
        __builtin_amdgcn_s_barrier();
        __builtin_amdgcn_sched_barrier(0);

        if (i == nt1) {
            const float inv = qmask[b * T + q] / lrun;
            __hip_bfloat16* orow = Oattn + (size_t)(b * T + q) * D + h * DH;
#pragma unroll
            for (int db = 0; db < 4; ++db) {
                union { ushort4 u4; unsigned short us[4]; } pk;
#pragma unroll
                for (int j = 0; j < 4; ++j)
                    pk.us[j] = bf16bits(o[db][j] * inv);
                *(ushort4*)(orow + db * 16 + hi * 4) = pk.u4;
            }
            qtile = 7 - pr;
            q = qtile * 64 + w * 16 + lo;
            const __hip_bfloat16* Qrow2 = Qbf + (size_t)(b * T + q) * D + h * DH;
            qf0 = *(const bf16x8*)(Qrow2 + hi * 8);
            qf1 = *(const bf16x8*)(Qrow2 + 32 + hi * 8);
            mrun = -INFINITY; lrun = 0.f;
#pragma unroll
            for (int d = 0; d < 4; ++d) o[d] = (f32x4){0.f, 0.f, 0.f, 0.f};
        }

        const int kt = (i < nt1) ? i : (i - nt1);
        const int kb = kt * 64;

        const __hip_bfloat16* Vtile = Vh + (size_t)kt * 4096;
        bf16x8 vf[4][2];
#pragma unroll
        for (int db = 0; db < 4; ++db) {
            const __hip_bfloat16* Vrow = Vtile + (db * 16 + lo) * 64;
            vf[db][0] = *(const bf16x8*)(Vrow + hi * 8);
            vf[db][1] = *(const bf16x8*)(Vrow + 32 + hi * 8);
        }

        bf16x8 kf[4][2];
#pragma unroll
        for (int c = 0; c < 4; ++c) {
            kf[c][0] = *(const bf16x8*)&Ks[cur][kfoff[c][0]];
            kf[c][1] = *(const bf16x8*)&Ks[cur][kfoff[c][1]];
        }

        // ---- S^T + additive masks ----
        f32x4 S[4];
#pragma unroll
        for (int c = 0; c < 4; ++c) {
            f32x4 acc = (f32x4){0.f, 0.f, 0.f, 0.f};
            acc = mfma16(kf[c][0], qf0, acc);
            acc = mfma16(kf[c][1], qf1, acc);
            acc += *(const f32x4*)(km + kb + c * 16 + hi * 4);
            if (diag) acc += cb[c];
            S[c] = acc;
        }

        float tm0 = fmaxf(fmaxf(S[0][0], S[0][1]), fmaxf(S[0][2], S[0][3]));
        float tm1 = fmaxf(fmaxf(S[1][0], S[1][1]), fmaxf(S[1][2], S[1][3]));
        float tm2 = fmaxf(fmaxf(S[2][0], S[2][1]), fmaxf(S[2][2], S[2][3]));
        float tm3 = fmaxf(fmaxf(S[3][0], S[3][1]), fmaxf(S[3][2], S[3][3]));
        float tm = fmaxf(fmaxf(tm0, tm1), fmaxf(tm2, tm3));
        tm = fmaxf(tm, __shfl_xor(tm, 16, 64));
        tm = fmaxf(tm, __shfl_xor(tm, 32, 64));

        const float nm = fmaxf(mrun, tm);
        const float alpha = fexp2(mrun - nm);
        mrun = nm;
#pragma unroll
        for (int d = 0; d < 4; ++d)
#pragma unroll
            for (int j = 0; j < 4; ++j)
                o[d][j] *= alpha;

        float ps = 0.f;
#pragma unroll
        for (int c = 0; c < 4; ++c) {
            union { ushort4 u4; unsigned short us[4]; } pk;
#pragma unroll
            for (int j = 0; j < 4; ++j) {
                float p = fexp2(S[c][j] - nm);
                ps += p;
                pk.us[j] = bf16bits(p);
            }
            *(ushort4*)&p_lds[w][lo][c * 16 + hi * 4] = pk.u4;
        }
        ps += __shfl_xor(ps, 16, 64);
        ps += __shfl_xor(ps, 32, 64);
        lrun = lrun * alpha + ps;

        asm volatile("s_waitcnt lgkmcnt(0)" ::: "memory");
        __builtin_amdgcn_sched_barrier(0);

#pragma unroll
        for (int half = 0; half < 2; ++half) {
            bf16x8 pf = *(const bf16x8*)&p_lds[w][lo][half * 32 + hi * 8];
#pragma unroll
            for (int db = 0; db < 4; ++db)
                o[db] = mfma16(vf[db][half], pf, o[db]);
        }

        __builtin_amdgcn_s_barrier();
    }

    {
        const float inv = qmask[b * T + q] / lrun;
        __hip_bfloat16* orow = Oattn + (size_t)(b * T + q) * D + h * DH;
#pragma unroll
        for (int db = 0; db < 4; ++db) {
            union { ushort4 u4; unsigned short us[4]; } pk;
#pragma unroll
            for (int j = 0; j < 4; ++j)
                pk.us[j] = bf16bits(o[db][j] * inv);
            *(ushort4*)(orow + db * 16 + hi * 4) = pk.u4;
        }
    }
#undef STAGEK
}

// ---------------------------------------------------------------------------
// Kernel 4: residual + LayerNorm (ddof=1, eps added to std).
// One WAVE per row: 8 elements/lane, shuffle-only reduction, no LDS/barriers.
// ---------------------------------------------------------------------------
__global__ __launch_bounds__(256) void resid_ln(
    const __hip_bfloat16* __restrict__ Oa, const float* __restrict__ queries,
    const float* __restrict__ gamma, const float* __restrict__ beta,
    float* __restrict__ out)
{
    const int w = threadIdx.x >> 6;
    const int lane = threadIdx.x & 63;
    const int row = blockIdx.x * 4 + w;
    const size_t base = (size_t)row * 512 + lane * 8;

    bf16x8 oa = *(const bf16x8*)((const unsigned short*)Oa + base);
    float4 q0 = *(const float4*)(queries + base);
    float4 q1 = *(const float4*)(queries + base + 4);

    float x[8];
    x[0] = b2f((unsigned short)oa[0]) + q0.x;
    x[1] = b2f((unsigned short)oa[1]) + q0.y;
    x[2] = b2f((unsigned short)oa[2]) + q0.z;
    x[3] = b2f((unsigned short)oa[3]) + q0.w;
    x[4] = b2f((unsigned short)oa[4]) + q1.x;
    x[5] = b2f((unsigned short)oa[5]) + q1.y;
    x[6] = b2f((unsigned short)oa[6]) + q1.z;
    x[7] = b2f((unsigned short)oa[7]) + q1.w;

    float s = ((x[0] + x[1]) + (x[2] + x[3])) + ((x[4] + x[5]) + (x[6] + x[7]));
#pragma unroll
    for (int off = 32; off > 0; off >>= 1) s += __shfl_xor(s, off, 64);
    const float mean = s * (1.0f / 512.0f);

    float d[8], ss = 0.f;
#pragma unroll
    for (int j = 0; j < 8; ++j) { d[j] = x[j] - mean; ss += d[j] * d[j]; }
#pragma unroll
    for (int off = 32; off > 0; off >>= 1) ss += __shfl_xor(ss, off, 64);
    const float denom = sqrtf(ss * (1.0f / 511.0f)) + LN_EPS;
    const float rden = 1.0f / denom;

    float4 g0 = *(const float4*)(gamma + lane * 8);
    float4 g1 = *(const float4*)(gamma + lane * 8 + 4);
    float4 b0 = *(const float4*)(beta + lane * 8);
    float4 b1 = *(const float4*)(beta + lane * 8 + 4);

    float4 r0, r1;
    r0.x = g0.x * d[0] * rden + b0.x;
    r0.y = g0.y * d[1] * rden + b0.y;
    r0.z = g0.z * d[2] * rden + b0.z;
    r0.w = g0.w * d[3] * rden + b0.w;
    r1.x = g1.x * d[4] * rden + b1.x;
    r1.y = g1.y * d[5] * rden + b1.y;
    r1.z = g1.z * d[6] * rden + b1.z;
    r1.w = g1.w * d[7] * rden + b1.w;
    *(float4*)(out + base) = r0;
    *(float4*)(out + base + 4) = r1;
}

// ---------------------------------------------------------------------------
extern "C" void kernel_launch(void* const* d_in, const int* in_sizes, int n_in,
                              void* d_out, int out_size, void* d_ws, size_t ws_size,
                              hipStream_t stream)
{
    const float* queries = (const float*)d_in[0];
    const float* keys    = (const float*)d_in[1];
    const float* Wq      = (const float*)d_in[2];
    const float* bq      = (const float*)d_in[3];
    const float* Wk      = (const float*)d_in[4];
    const float* bk      = (const float*)d_in[5];
    const float* Wv      = (const float*)d_in[6];
    const float* bv      = (const float*)d_in[7];
    const float* gamma   = (const float*)d_in[8];
    const float* beta    = (const float*)d_in[9];
    float* out = (float*)d_out;

    char* ws = (char*)d_ws;
    __hip_bfloat16* Qbf   = (__hip_bfloat16*)(ws);                  // 16 MB
    __hip_bfloat16* Kbf   = (__hip_bfloat16*)(ws + 16777216);       // 16 MB
    __hip_bfloat16* Vtb   = (__hip_bfloat16*)(ws + 33554432);       // 16 MB
    __hip_bfloat16* Qx    = (__hip_bfloat16*)(ws + 50331648);       // 16 MB
    __hip_bfloat16* Oattn = (__hip_bfloat16*)(ws + 50331648);       // aliases Qx (dead)
    __hip_bfloat16* Kx    = (__hip_bfloat16*)(ws + 67108864);       // 16 MB
    __hip_bfloat16* Wbf   = (__hip_bfloat16*)(ws + 83886080);       // 1.5 MB
    float* qmask          = (float*)(ws + 85458944);                // 64 KB
    float* kmask          = (float*)(ws + 85524480);                // 64 KB

    convert_all<<<dim3(4288, 2), 256, 0, stream>>>(
        queries, keys, Wq, Wk, Wv, Qx, Kx, Wbf, qmask, kmask);
    qkv_qk<<<dim3(128, 4, 2), 256, 0, stream>>>(
        Qx, Kx, Wbf, bq, bk, Qbf, Kbf);
    qkv_v<<<dim3(128, 4), 256, 0, stream>>>(Kx, Wbf, bv, Vtb);
    flash_attn<<<dim3(4, 8, 32), 256, 0, stream>>>(
        Qbf, Kbf, Vtb, qmask, kmask, Oattn);
    resid_ln<<<4096, 256, 0, stream>>>(Oattn, queries, gamma, beta, out);
}

// Round 15
// 113.432 us; speedup vs baseline: 1.2904x; 1.1304x over previous
//
#include <hip/hip_runtime.h>
#include <hip/hip_bf16.h>
#include <math.h>

#define B 32
#define T 512
#define D 512
#define H 8
#define DH 64
#define NEGV (-4294967295.0f)   // -(2^32) + 1
#define LN_EPS 1e-8f

typedef __attribute__((ext_vector_type(8))) short bf16x8;
typedef __attribute__((ext_vector_type(4))) float f32x4;

__device__ inline f32x4 mfma16(bf16x8 a, bf16x8 b, f32x4 c) {
    return __builtin_amdgcn_mfma_f32_16x16x32_bf16(a, b, c, 0, 0, 0);
}

__device__ inline float fexp2(float x) { return __builtin_amdgcn_exp2f(x); }

#define GLDS16(g, l)                                                      \
    __builtin_amdgcn_global_load_lds(                                     \
        (const __attribute__((address_space(1))) void*)(g),               \
        (__attribute__((address_space(3))) void*)(l), 16, 0, 0)

__device__ inline unsigned short bf16bits(float x) {
    __hip_bfloat16 h = __float2bfloat16(x);
    union { __hip_bfloat16 h; unsigned short u; } cv;
    cv.h = h;
    return cv.u;
}

__device__ inline float b2f(unsigned short u) {
    union { unsigned u; float f; } c;
    c.u = ((unsigned)u) << 16;
    return c.f;
}

// ---------------------------------------------------------------------------
// Kernel 1: convert queries/keys -> bf16 + row masks + W -> bf16 (merged).
// ---------------------------------------------------------------------------
__global__ __launch_bounds__(256) void convert_all(
    const float* __restrict__ queries, const float* __restrict__ keys,
    const float* __restrict__ Wq, const float* __restrict__ Wk,
    const float* __restrict__ Wv,
    __hip_bfloat16* __restrict__ Qx, __hip_bfloat16* __restrict__ Kx,
    __hip_bfloat16* __restrict__ Wbf,
    float* __restrict__ qmask, float* __restrict__ kmask)
{
    const int tid = threadIdx.x;
    if (blockIdx.x >= 4096) {
        const int i = (blockIdx.x - 4096) * 2 + blockIdx.y;   // 0..383
        const int mat = i >> 7;
        const float* Ws = (mat == 0) ? Wq : (mat == 1) ? Wk : Wv;
        const int idx = ((i & 127) * 256 + tid) * 8;
        float4 a = *(const float4*)&Ws[idx];
        float4 c = *(const float4*)&Ws[idx + 4];
        union { unsigned short u[8]; bf16x8 v; } pk;
        pk.u[0] = bf16bits(a.x); pk.u[1] = bf16bits(a.y);
        pk.u[2] = bf16bits(a.z); pk.u[3] = bf16bits(a.w);
        pk.u[4] = bf16bits(c.x); pk.u[5] = bf16bits(c.y);
        pk.u[6] = bf16bits(c.z); pk.u[7] = bf16bits(c.w);
        *(bf16x8*)&Wbf[(size_t)mat * 262144 + idx] = pk.v;
        return;
    }

    const int wid = tid >> 6;
    const int lane = tid & 63;
    const int row = blockIdx.x * 4 + wid;
    const float* src = blockIdx.y ? keys : queries;
    __hip_bfloat16* dst = blockIdx.y ? Kx : Qx;
    float* dm = blockIdx.y ? kmask : qmask;

    const float4* p = (const float4*)(src + (size_t)row * 512);
    float4 a = p[lane * 2];
    float4 c = p[lane * 2 + 1];
    float s = a.x + a.y + a.z + a.w + c.x + c.y + c.z + c.w;

    union { unsigned short u[8]; bf16x8 v; } pk;
    pk.u[0] = bf16bits(a.x); pk.u[1] = bf16bits(a.y);
    pk.u[2] = bf16bits(a.z); pk.u[3] = bf16bits(a.w);
    pk.u[4] = bf16bits(c.x); pk.u[5] = bf16bits(c.y);
    pk.u[6] = bf16bits(c.z); pk.u[7] = bf16bits(c.w);
    *(bf16x8*)&dst[(size_t)row * 512 + lane * 8] = pk.v;

#pragma unroll
    for (int off = 32; off > 0; off >>= 1) s += __shfl_xor(s, off, 64);
    if (lane == 0)
        dm[row] = blockIdx.y ? ((s != 0.0f) ? 0.0f : NEGV)
                             : ((s != 0.0f) ? 1.0f : 0.0f);
}

// ---------------------------------------------------------------------------
// Kernel 2a: Q/K projection, bf16 MFMA, SWAPPED operands mfma(W, X).
// ---------------------------------------------------------------------------
__global__ __launch_bounds__(256) void qkv_qk(
    const __hip_bfloat16* __restrict__ Qx, const __hip_bfloat16* __restrict__ Kx,
    const __hip_bfloat16* __restrict__ Wbf,
    const float* __restrict__ bq, const float* __restrict__ bk,
    __hip_bfloat16* __restrict__ Qbf, __hip_bfloat16* __restrict__ Kbf)
{
    const int mat = blockIdx.z;
    const __hip_bfloat16* X  = mat ? Kx : Qx;
    const __hip_bfloat16* Wm = Wbf + (size_t)mat * 262144;
    const float* bias = mat ? bk : bq;
    __hip_bfloat16* Out = mat ? Kbf : Qbf;
    const float sc = mat ? 1.0f : 0.18033688011112042f;

    const int bm = blockIdx.x * 128;
    const int bn = blockIdx.y * 128;
    const int tid = threadIdx.x;
    const int w = tid >> 6, lane = tid & 63;
    const int lo = lane & 15, hi = lane >> 4;
    const int wm = (w >> 1) * 64, wn = (w & 1) * 64;

    __shared__ __hip_bfloat16 As[2][128 * 32];
    __shared__ __hip_bfloat16 Bs[2][128 * 32];

    const int r0 = tid >> 2,          g0 = (tid & 3) ^ ((r0 >> 1) & 3);
    const int r1 = (tid + 256) >> 2,  g1 = ((tid + 256) & 3) ^ ((r1 >> 1) & 3);
    const __hip_bfloat16* sA0 = X  + (size_t)(bm + r0) * 512 + g0 * 8;
    const __hip_bfloat16* sA1 = X  + (size_t)(bm + r1) * 512 + g1 * 8;
    const __hip_bfloat16* sB0 = Wm + (size_t)(bn + r0) * 512 + g0 * 8;
    const __hip_bfloat16* sB1 = Wm + (size_t)(bn + r1) * 512 + g1 * 8;
    const int dst0 = (w * 64) * 8;
    const int dst1 = (256 + w * 64) * 8;

    int offA[4], offB[4];
#pragma unroll
    for (int mi = 0; mi < 4; ++mi) {
        int r = wm + mi * 16 + lo;
        offA[mi] = r * 32 + ((hi ^ ((r >> 1) & 3)) * 8);
    }
#pragma unroll
    for (int ni = 0; ni < 4; ++ni) {
        int r = wn + ni * 16 + lo;
        offB[ni] = r * 32 + ((hi ^ ((r >> 1) & 3)) * 8);
    }

    f32x4 acc[4][4];
#pragma unroll
    for (int mi = 0; mi < 4; ++mi)
#pragma unroll
        for (int ni = 0; ni < 4; ++ni)
            acc[mi][ni] = (f32x4){0.f, 0.f, 0.f, 0.f};

    GLDS16(sA0, &As[0][dst0]);
    GLDS16(sA1, &As[0][dst1]);
    GLDS16(sB0, &Bs[0][dst0]);
    GLDS16(sB1, &Bs[0][dst1]);
    __syncthreads();

    for (int kt = 0; kt < 16; ++kt) {
        const int cur = kt & 1;
        if (kt < 15) {
            const int k0 = (kt + 1) * 32;
            GLDS16(sA0 + k0, &As[cur ^ 1][dst0]);
            GLDS16(sA1 + k0, &As[cur ^ 1][dst1]);
            GLDS16(sB0 + k0, &Bs[cur ^ 1][dst0]);
            GLDS16(sB1 + k0, &Bs[cur ^ 1][dst1]);
        }
        bf16x8 af[4], bfr[4];
#pragma unroll
        for (int mi = 0; mi < 4; ++mi) af[mi]  = *(const bf16x8*)&As[cur][offA[mi]];
#pragma unroll
        for (int ni = 0; ni < 4; ++ni) bfr[ni] = *(const bf16x8*)&Bs[cur][offB[ni]];
#pragma unroll
        for (int mi = 0; mi < 4; ++mi)
#pragma unroll
            for (int ni = 0; ni < 4; ++ni)
                acc[mi][ni] = mfma16(bfr[ni], af[mi], acc[mi][ni]);
        __syncthreads();
    }

    float4 b4[4];
#pragma unroll
    for (int ni = 0; ni < 4; ++ni)
        b4[ni] = *(const float4*)&bias[bn + wn + ni * 16 + hi * 4];
#pragma unroll
    for (int mi = 0; mi < 4; ++mi) {
        const size_t tok = bm + wm + mi * 16 + lo;
        __hip_bfloat16* orow = Out + tok * 512 + bn + wn + hi * 4;
#pragma unroll
        for (int ni = 0; ni < 4; ++ni) {
            union { ushort4 u4; unsigned short us[4]; } pk;
            pk.us[0] = bf16bits((acc[mi][ni][0] + b4[ni].x) * sc);
            pk.us[1] = bf16bits((acc[mi][ni][1] + b4[ni].y) * sc);
            pk.us[2] = bf16bits((acc[mi][ni][2] + b4[ni].z) * sc);
            pk.us[3] = bf16bits((acc[mi][ni][3] + b4[ni].w) * sc);
            *(ushort4*)(orow + ni * 16) = pk.u4;
        }
    }
}

// ---------------------------------------------------------------------------
// Kernel 2b: V projection, bf16 MFMA, original order mfma(X, W).
// ---------------------------------------------------------------------------
__global__ __launch_bounds__(256) void qkv_v(
    const __hip_bfloat16* __restrict__ Kx, const __hip_bfloat16* __restrict__ Wbf,
    const float* __restrict__ bv, __hip_bfloat16* __restrict__ Vtb)
{
    const __hip_bfloat16* X  = Kx;
    const __hip_bfloat16* Wm = Wbf + (size_t)2 * 262144;
    const float* bias = bv;

    const int bm = blockIdx.x * 128;
    const int bn = blockIdx.y * 128;
    const int tid = threadIdx.x;
    const int w = tid >> 6, lane = tid & 63;
    const int lo = lane & 15, hi = lane >> 4;
    const int wm = (w >> 1) * 64, wn = (w & 1) * 64;

    __shared__ __hip_bfloat16 As[2][128 * 32];
    __shared__ __hip_bfloat16 Bs[2][128 * 32];

    const int r0 = tid >> 2,          g0 = (tid & 3) ^ ((r0 >> 1) & 3);
    const int r1 = (tid + 256) >> 2,  g1 = ((tid + 256) & 3) ^ ((r1 >> 1) & 3);
    const __hip_bfloat16* sA0 = X  + (size_t)(bm + r0) * 512 + g0 * 8;
    const __hip_bfloat16* sA1 = X  + (size_t)(bm + r1) * 512 + g1 * 8;
    const __hip_bfloat16* sB0 = Wm + (size_t)(bn + r0) * 512 + g0 * 8;
    const __hip_bfloat16* sB1 = Wm + (size_t)(bn + r1) * 512 + g1 * 8;
    const int dst0 = (w * 64) * 8;
    const int dst1 = (256 + w * 64) * 8;

    int offA[4], offB[4];
#pragma unroll
    for (int mi = 0; mi < 4; ++mi) {
        int r = wm + mi * 16 + lo;
        offA[mi] = r * 32 + ((hi ^ ((r >> 1) & 3)) * 8);
    }
#pragma unroll
    for (int ni = 0; ni < 4; ++ni) {
        int r = wn + ni * 16 + lo;
        offB[ni] = r * 32 + ((hi ^ ((r >> 1) & 3)) * 8);
    }

    f32x4 acc[4][4];
#pragma unroll
    for (int mi = 0; mi < 4; ++mi)
#pragma unroll
        for (int ni = 0; ni < 4; ++ni)
            acc[mi][ni] = (f32x4){0.f, 0.f, 0.f, 0.f};

    GLDS16(sA0, &As[0][dst0]);
    GLDS16(sA1, &As[0][dst1]);
    GLDS16(sB0, &Bs[0][dst0]);
    GLDS16(sB1, &Bs[0][dst1]);
    __syncthreads();

    for (int kt = 0; kt < 16; ++kt) {
        const int cur = kt & 1;
        if (kt < 15) {
            const int k0 = (kt + 1) * 32;
            GLDS16(sA0 + k0, &As[cur ^ 1][dst0]);
            GLDS16(sA1 + k0, &As[cur ^ 1][dst1]);
            GLDS16(sB0 + k0, &Bs[cur ^ 1][dst0]);
            GLDS16(sB1 + k0, &Bs[cur ^ 1][dst1]);
        }
        bf16x8 af[4], bfr[4];
#pragma unroll
        for (int mi = 0; mi < 4; ++mi) af[mi]  = *(const bf16x8*)&As[cur][offA[mi]];
#pragma unroll
        for (int ni = 0; ni < 4; ++ni) bfr[ni] = *(const bf16x8*)&Bs[cur][offB[ni]];
#pragma unroll
        for (int mi = 0; mi < 4; ++mi)
#pragma unroll
            for (int ni = 0; ni < 4; ++ni)
                acc[mi][ni] = mfma16(af[mi], bfr[ni], acc[mi][ni]);
        __syncthreads();
    }

    float bcol[4];
#pragma unroll
    for (int ni = 0; ni < 4; ++ni) bcol[ni] = bias[bn + wn + ni * 16 + lo];
    const int bb = bm >> 9;
    const int tb = (bm & 511) + wm;
#pragma unroll
    for (int ni = 0; ni < 4; ++ni) {
        const int n = bn + wn + ni * 16 + lo;
        const int hh = n >> 6, dh = n & 63;
#pragma unroll
        for (int mi = 0; mi < 4; ++mi) {
            const int tok = tb + mi * 16 + hi * 4;
            const int ktl = tok >> 6, tl = tok & 63;
            union { ushort4 u4; unsigned short us[4]; } pk;
#pragma unroll
            for (int j = 0; j < 4; ++j)
                pk.us[j] = bf16bits(acc[mi][ni][j] + bcol[ni]);
            *(ushort4*)(Vtb + ((((size_t)(bb * 8 + hh) * 8 + ktl) * 64 + dh) * 64 + tl))
                = pk.u4;
        }
    }
}

// ---------------------------------------------------------------------------
// Kernel 3: flash attention — round-12 tight pipeline, now 32 q-rows/wave:
// block = 128 q-rows (groups g and 3-g paired -> uniform 10 iterations).
// Per iteration K/V/km loads are fragment-shared; MFMA per iteration doubles
// (16 QK + 16 PV); barriers per q-row halve.  Wave-uniform skip of tiles
// beyond the wave's causal bound tqw.  Grid 512 blocks, launch_bounds(256,2).
// ---------------------------------------------------------------------------
__global__ __launch_bounds__(256, 2) void flash_attn(
    const __hip_bfloat16* __restrict__ Qbf, const __hip_bfloat16* __restrict__ Kbf,
    const __hip_bfloat16* __restrict__ Vtb, const float* __restrict__ qmask,
    const float* __restrict__ kmneg, __hip_bfloat16* __restrict__ Oattn)
{
    const int flat = blockIdx.x + (blockIdx.y << 1) + (blockIdx.z << 4); // 512
    const int rm = ((flat & 7) << 6) + (flat >> 3);   // XCD chunks of 64
    const int pg = rm & 1;            // pair index: groups pg / 3-pg
    const int h  = (rm >> 1) & 7;
    const int b  = rm >> 4;

    const int tid  = threadIdx.x;
    const int w    = tid >> 6;
    const int lane = tid & 63;
    const int lo = lane & 15;
    const int hi = lane >> 4;

    __shared__ __hip_bfloat16 Ks[2][4096];
    __shared__ __hip_bfloat16 p_lds[4][2][16][72];

    const float* km = kmneg + b * T;
    const __hip_bfloat16* Kh = Kbf + (size_t)b * T * D + h * DH;
    const __hip_bfloat16* Vh = Vtb + (size_t)(b * H + h) * T * DH;

    const int sr0 = tid >> 3,         sg0 = (tid & 7) ^ (sr0 & 7);
    const int sr1 = (tid + 256) >> 3, sg1 = ((tid + 256) & 7) ^ (sr1 & 7);
    const __hip_bfloat16* sK0 = Kh + (size_t)sr0 * 512 + sg0 * 8;
    const __hip_bfloat16* sK1 = Kh + (size_t)sr1 * 512 + sg1 * 8;
    __hip_bfloat16* dK0a = &Ks[0][w * 512];
    __hip_bfloat16* dK0b = &Ks[0][2048 + w * 512];
    __hip_bfloat16* dK1a = &Ks[1][w * 512];
    __hip_bfloat16* dK1b = &Ks[1][2048 + w * 512];

#define STAGEK(bufp, kt) do {                                              \
        const size_t _o = (size_t)(kt) * 32768;                            \
        GLDS16(sK0 + _o, (bufp) ? dK1a : dK0a);                            \
        GLDS16(sK1 + _o, (bufp) ? dK1b : dK0b);                            \
    } while (0)

    int kfoff[4][2];
#pragma unroll
    for (int c = 0; c < 4; ++c)
#pragma unroll
        for (int j = 0; j < 2; ++j)
            kfoff[c][j] = (c * 16 + lo) * 64 + (((j * 4 + hi) ^ (lo & 7)) * 8);

    // per-fragment local q index within its diagonal 64-tile
    const int qloc0 = (32 * w + lo) & 63;
    const int qloc1 = (32 * w + 16 + lo) & 63;

    const int len1 = 2 * pg + 2;      // pass-1 iterations

    int g = pg;
    int tqw = 2 * g + (w >> 1);       // wave's causal tile bound
    int qb = g * 128 + w * 32 + lo;   // fragment-0 q row

    bf16x8 qf[2][2];
    {
        const __hip_bfloat16* Q0 = Qbf + (size_t)(b * T + qb) * D + h * DH;
        qf[0][0] = *(const bf16x8*)(Q0 + hi * 8);
        qf[0][1] = *(const bf16x8*)(Q0 + 32 + hi * 8);
        const __hip_bfloat16* Q1 = Q0 + (size_t)16 * D;
        qf[1][0] = *(const bf16x8*)(Q1 + hi * 8);
        qf[1][1] = *(const bf16x8*)(Q1 + 32 + hi * 8);
    }

    f32x4 o[2][4];
    float mrun[2], lrun[2];
#pragma unroll
    for (int f = 0; f < 2; ++f) {
        mrun[f] = -INFINITY; lrun[f] = 0.f;
#pragma unroll
        for (int d = 0; d < 4; ++d) o[f][d] = (f32x4){0.f, 0.f, 0.f, 0.f};
    }

    STAGEK(0, 0);

    for (int i = 0; i < 10; ++i) {
        const int cur = i & 1;
        if (i < 9) {
            const int nkt = (i + 1 < len1) ? (i + 1) : (i + 1 - len1);
            STAGEK(cur ^ 1, nkt);
            asm volatile("s_waitcnt vmcnt(2)" ::: "memory");
        } else {
            asm volatile("s_waitcnt vmcnt(0)" ::: "memory");
        }
        __builtin_amdgcn_s_barrier();
        __builtin_amdgcn_sched_barrier(0);

        if (i == len1) {
            // pass-1 epilogue (both fragments), then switch to group 3-pg
#pragma unroll
            for (int f = 0; f < 2; ++f) {
                const int qr = qb + f * 16;
                const float inv = qmask[b * T + qr] / lrun[f];
                __hip_bfloat16* orow = Oattn + (size_t)(b * T + qr) * D + h * DH;
#pragma unroll
                for (int db = 0; db < 4; ++db) {
                    union { ushort4 u4; unsigned short us[4]; } pk;
#pragma unroll
                    for (int j = 0; j < 4; ++j)
                        pk.us[j] = bf16bits(o[f][db][j] * inv);
                    *(ushort4*)(orow + db * 16 + hi * 4) = pk.u4;
                }
            }
            g = 3 - pg;
            tqw = 2 * g + (w >> 1);
            qb = g * 128 + w * 32 + lo;
            const __hip_bfloat16* Q0 = Qbf + (size_t)(b * T + qb) * D + h * DH;
            qf[0][0] = *(const bf16x8*)(Q0 + hi * 8);
            qf[0][1] = *(const bf16x8*)(Q0 + 32 + hi * 8);
            const __hip_bfloat16* Q1 = Q0 + (size_t)16 * D;
            qf[1][0] = *(const bf16x8*)(Q1 + hi * 8);
            qf[1][1] = *(const bf16x8*)(Q1 + 32 + hi * 8);
#pragma unroll
            for (int f = 0; f < 2; ++f) {
                mrun[f] = -INFINITY; lrun[f] = 0.f;
#pragma unroll
                for (int d = 0; d < 4; ++d) o[f][d] = (f32x4){0.f, 0.f, 0.f, 0.f};
            }
        }

        const int kt = (i < len1) ? i : (i - len1);

        if (kt <= tqw) {              // wave-uniform causal skip
            const int kb = kt * 64;
            const bool diag = (kt == tqw);

            f32x4 kmb[4];
#pragma unroll
            for (int c = 0; c < 4; ++c)
                kmb[c] = *(const f32x4*)(km + kb + c * 16 + hi * 4);

            const __hip_bfloat16* Vtile = Vh + (size_t)kt * 4096;
            bf16x8 vf[4][2];
#pragma unroll
            for (int db = 0; db < 4; ++db) {
                const __hip_bfloat16* Vrow = Vtile + (db * 16 + lo) * 64;
                vf[db][0] = *(const bf16x8*)(Vrow + hi * 8);
                vf[db][1] = *(const bf16x8*)(Vrow + 32 + hi * 8);
            }

            bf16x8 kf[4][2];
#pragma unroll
            for (int c = 0; c < 4; ++c) {
                kf[c][0] = *(const bf16x8*)&Ks[cur][kfoff[c][0]];
                kf[c][1] = *(const bf16x8*)&Ks[cur][kfoff[c][1]];
            }

#pragma unroll
            for (int f = 0; f < 2; ++f) {
                const int qloc = f ? qloc1 : qloc0;
                f32x4 S[4];
#pragma unroll
                for (int c = 0; c < 4; ++c) {
                    f32x4 acc = (f32x4){0.f, 0.f, 0.f, 0.f};
                    acc = mfma16(kf[c][0], qf[f][0], acc);
                    acc = mfma16(kf[c][1], qf[f][1], acc);
                    acc += kmb[c];
                    if (diag) {
#pragma unroll
                        for (int j = 0; j < 4; ++j)
                            acc[j] = (c * 16 + hi * 4 + j <= qloc) ? acc[j] : NEGV;
                    }
                    S[c] = acc;
                }

                float tm0 = fmaxf(fmaxf(S[0][0], S[0][1]), fmaxf(S[0][2], S[0][3]));
                float tm1 = fmaxf(fmaxf(S[1][0], S[1][1]), fmaxf(S[1][2], S[1][3]));
                float tm2 = fmaxf(fmaxf(S[2][0], S[2][1]), fmaxf(S[2][2], S[2][3]));
                float tm3 = fmaxf(fmaxf(S[3][0], S[3][1]), fmaxf(S[3][2], S[3][3]));
                float tm = fmaxf(fmaxf(tm0, tm1), fmaxf(tm2, tm3));
                tm = fmaxf(tm, __shfl_xor(tm, 16, 64));
                tm = fmaxf(tm, __shfl_xor(tm, 32, 64));

                const float nm = fmaxf(mrun[f], tm);
                const float alpha = fexp2(mrun[f] - nm);
                mrun[f] = nm;
#pragma unroll
                for (int d = 0; d < 4; ++d)
#pragma unroll
                    for (int j = 0; j < 4; ++j)
                        o[f][d][j] *= alpha;

                float ps = 0.f;
#pragma unroll
                for (int c = 0; c < 4; ++c) {
                    union { ushort4 u4; unsigned short us[4]; } pk;
#pragma unroll
                    for (int j = 0; j < 4; ++j) {
                        float p = fexp2(S[c][j] - nm);
                        ps += p;
                        pk.us[j] = bf16bits(p);
                    }
                    *(ushort4*)&p_lds[w][f][lo][c * 16 + hi * 4] = pk.u4;
                }
                ps += __shfl_xor(ps, 16, 64);
                ps += __shfl_xor(ps, 32, 64);
                lrun[f] = lrun[f] * alpha + ps;
            }

            // same-wave LDS write -> read fence (p_lds slices are per-wave)
            asm volatile("s_waitcnt lgkmcnt(0)" ::: "memory");
            __builtin_amdgcn_sched_barrier(0);

#pragma unroll
            for (int half = 0; half < 2; ++half) {
                bf16x8 pf0 = *(const bf16x8*)&p_lds[w][0][lo][half * 32 + hi * 8];
                bf16x8 pf1 = *(const bf16x8*)&p_lds[w][1][lo][half * 32 + hi * 8];
#pragma unroll
                for (int db = 0; db < 4; ++db) {
                    o[0][db] = mfma16(vf[db][half], pf0, o[0][db]);
                    o[1][db] = mfma16(vf[db][half], pf1, o[1][db]);
                }
            }
        }

        __builtin_amdgcn_s_barrier();
    }

    // pass-2 epilogue (both fragments)
#pragma unroll
    for (int f = 0; f < 2; ++f) {
        const int qr = qb + f * 16;
        const float inv = qmask[b * T + qr] / lrun[f];
        __hip_bfloat16* orow = Oattn + (size_t)(b * T + qr) * D + h * DH;
#pragma unroll
        for (int db = 0; db < 4; ++db) {
            union { ushort4 u4; unsigned short us[4]; } pk;
#pragma unroll
            for (int j = 0; j < 4; ++j)
                pk.us[j] = bf16bits(o[f][db][j] * inv);
            *(ushort4*)(orow + db * 16 + hi * 4) = pk.u4;
        }
    }
#undef STAGEK
}

// ---------------------------------------------------------------------------
// Kernel 4: residual + LayerNorm (ddof=1, eps added to std).
// One WAVE per row: 8 elements/lane, shuffle-only reduction.
// ---------------------------------------------------------------------------
__global__ __launch_bounds__(256) void resid_ln(
    const __hip_bfloat16* __restrict__ Oa, const float* __restrict__ queries,
    const float* __restrict__ gamma, const float* __restrict__ beta,
    float* __restrict__ out)
{
    const int w = threadIdx.x >> 6;
    const int lane = threadIdx.x & 63;
    const int row = blockIdx.x * 4 + w;
    const size_t base = (size_t)row * 512 + lane * 8;

    bf16x8 oa = *(const bf16x8*)((const unsigned short*)Oa + base);
    float4 q0 = *(const float4*)(queries + base);
    float4 q1 = *(const float4*)(queries + base + 4);

    float x[8];
    x[0] = b2f((unsigned short)oa[0]) + q0.x;
    x[1] = b2f((unsigned short)oa[1]) + q0.y;
    x[2] = b2f((unsigned short)oa[2]) + q0.z;
    x[3] = b2f((unsigned short)oa[3]) + q0.w;
    x[4] = b2f((unsigned short)oa[4]) + q1.x;
    x[5] = b2f((unsigned short)oa[5]) + q1.y;
    x[6] = b2f((unsigned short)oa[6]) + q1.z;
    x[7] = b2f((unsigned short)oa[7]) + q1.w;

    float s = ((x[0] + x[1]) + (x[2] + x[3])) + ((x[4] + x[5]) + (x[6] + x[7]));
#pragma unroll
    for (int off = 32; off > 0; off >>= 1) s += __shfl_xor(s, off, 64);
    const float mean = s * (1.0f / 512.0f);

    float d[8], ss = 0.f;
#pragma unroll
    for (int j = 0; j < 8; ++j) { d[j] = x[j] - mean; ss += d[j] * d[j]; }
#pragma unroll
    for (int off = 32; off > 0; off >>= 1) ss += __shfl_xor(ss, off, 64);
    const float denom = sqrtf(ss * (1.0f / 511.0f)) + LN_EPS;
    const float rden = 1.0f / denom;

    float4 g0 = *(const float4*)(gamma + lane * 8);
    float4 g1 = *(const float4*)(gamma + lane * 8 + 4);
    float4 b0 = *(const float4*)(beta + lane * 8);
    float4 b1 = *(const float4*)(beta + lane * 8 + 4);

    float4 r0, r1;
    r0.x = g0.x * d[0] * rden + b0.x;
    r0.y = g0.y * d[1] * rden + b0.y;
    r0.z = g0.z * d[2] * rden + b0.z;
    r0.w = g0.w * d[3] * rden + b0.w;
    r1.x = g1.x * d[4] * rden + b1.x;
    r1.y = g1.y * d[5] * rden + b1.y;
    r1.z = g1.z * d[6] * rden + b1.z;
    r1.w = g1.w * d[7] * rden + b1.w;
    *(float4*)(out + base) = r0;
    *(float4*)(out + base + 4) = r1;
}

// ---------------------------------------------------------------------------
extern "C" void kernel_launch(void* const* d_in, const int* in_sizes, int n_in,
                              void* d_out, int out_size, void* d_ws, size_t ws_size,
                              hipStream_t stream)
{
    const float* queries = (const float*)d_in[0];
    const float* keys    = (const float*)d_in[1];
    const float* Wq      = (const float*)d_in[2];
    const float* bq      = (const float*)d_in[3];
    const float* Wk      = (const float*)d_in[4];
    const float* bk      = (const float*)d_in[5];
    const float* Wv      = (const float*)d_in[6];
    const float* bv      = (const float*)d_in[7];
    const float* gamma   = (const float*)d_in[8];
    const float* beta    = (const float*)d_in[9];
    float* out = (float*)d_out;

    char* ws = (char*)d_ws;
    __hip_bfloat16* Qbf   = (__hip_bfloat16*)(ws);                  // 16 MB
    __hip_bfloat16* Kbf   = (__hip_bfloat16*)(ws + 16777216);       // 16 MB
    __hip_bfloat16* Vtb   = (__hip_bfloat16*)(ws + 33554432);       // 16 MB
    __hip_bfloat16* Qx    = (__hip_bfloat16*)(ws + 50331648);       // 16 MB
    __hip_bfloat16* Oattn = (__hip_bfloat16*)(ws + 50331648);       // aliases Qx (dead)
    __hip_bfloat16* Kx    = (__hip_bfloat16*)(ws + 67108864);       // 16 MB
    __hip_bfloat16* Wbf   = (__hip_bfloat16*)(ws + 83886080);       // 1.5 MB
    float* qmask          = (float*)(ws + 85458944);                // 64 KB
    float* kmask          = (float*)(ws + 85524480);                // 64 KB

    convert_all<<<dim3(4288, 2), 256, 0, stream>>>(
        queries, keys, Wq, Wk, Wv, Qx, Kx, Wbf, qmask, kmask);
    qkv_qk<<<dim3(128, 4, 2), 256, 0, stream>>>(
        Qx, Kx, Wbf, bq, bk, Qbf, Kbf);
    qkv_v<<<dim3(128, 4), 256, 0, stream>>>(Kx, Wbf, bv, Vtb);
    flash_attn<<<dim3(2, 8, 32), 256, 0, stream>>>(
        Qbf, Kbf, Vtb, qmask, kmask, Oattn);
    resid_ln<<<4096, 256, 0, stream>>>(Oattn, queries, gamma, beta, out);
}